// Round 11
// baseline (113.550 us; speedup 1.0000x reference)
//
#include <hip/hip_runtime.h>

#define NNODES 100000
#define NEDGES 3200000
#define CH     128
#define KPOOL  50000
#define NBUCK  (1 << 15)          // value buckets for f64 ranking
#define BUCK_SCALE 2048.0         // NBUCK / 16 (range [-8, 8))

// output offsets (floats)
#define OFF_X   0
#define OFF_EI  6400000
#define OFF_EA  12800000
#define OFF_REG 16000000
#define OFF_BAT 16050000
#define OFF_SC  16100000
#define OFF_NE  16200000

#define SCORE_BLK 391             // score blocks (256 rows each, thread-per-row)
#define FILL_BLK  2344            // prefill blocks (2.4M float4 / 1024)
#define EPB       2048            // edges per edge chunk
#define NBE       1563            // ceil(NEDGES / EPB)
#define POOLG     6250            // pool blocks (8 rows each)

// ws layout (bytes); zero region = [WS_HIST, WS_BBASE)
#define WS_SCORE  0               // 800,000
#define WS_HIST   800000          // 131,072
#define WS_KB     931072          //  12,544
#define WS_BBASE  943616          // 131,072
#define WS_SPART  1074688         //     128
#define WS_ELEMS  1074816         // 400,000
#define WS_PERM   1474816         // 200,000
#define WS_EPART  1674816         //   6,252
#define ZERO_U4   8976            // (943616 - 800000) / 16

__device__ __forceinline__ int bucketOf(double s) {
    double u = (8.0 - s) * BUCK_SCALE;   // monotonic: score desc -> bucket asc
    int b = (int)u;
    if (b < 0) b = 0;
    if (b > NBUCK - 1) b = NBUCK - 1;
    return b;
}

// Z: zero hist + kb (contiguous)
__global__ void k_init(uint4* __restrict__ z) {
    int idx = blockIdx.x * 256 + threadIdx.x;
    if (idx < ZERO_U4) z[idx] = make_uint4(0u, 0u, 0u, 0u);
}

// K1: scores (thread-per-row, 8-deep float4 MLP, serial f64 accum) + fused prefill
__global__ void k_scores_fill(const float* __restrict__ x, const float* __restrict__ W,
                              const float* __restrict__ bias, double* __restrict__ score_d,
                              float* __restrict__ out, unsigned* __restrict__ hist) {
    int bid = blockIdx.x, tid = threadIdx.x;
    if (bid < SCORE_BLK) {
        int row = bid * 256 + tid;
        if (row < NNODES) {
            const float4* xp = (const float4*)(x + (size_t)row * CH);
            double acc = 0.0;
#pragma unroll
            for (int g = 0; g < 4; ++g) {
                float4 v[8];
#pragma unroll
                for (int q = 0; q < 8; ++q) v[q] = xp[g * 8 + q];
#pragma unroll
                for (int q = 0; q < 8; ++q) {
                    const float* wp = W + (g * 8 + q) * 4;
                    acc += (double)v[q].x * (double)wp[0] + (double)v[q].y * (double)wp[1]
                         + (double)v[q].z * (double)wp[2] + (double)v[q].w * (double)wp[3];
                }
            }
            double s = acc + (double)bias[0];
            score_d[row] = s;
            out[OFF_SC + row] = (float)s;
            atomicAdd(&hist[bucketOf(s)], 1u);
        }
    } else {
        int fb = bid - SCORE_BLK;
        float4* dst = (float4*)(out + OFF_EI);
        const float4 neg = make_float4(-1.f, -1.f, -1.f, -1.f);
        const float4 zer = make_float4(0.f, 0.f, 0.f, 0.f);
#pragma unroll
        for (int q = 0; q < 4; ++q) {
            int f = fb * 1024 + q * 256 + tid;
            if (f < 2400000) dst[f] = (f < 1600000) ? neg : zer;
        }
    }
}

// S1: 32 blocks scan 1024 buckets each -> local-exclusive bases + block totals
__global__ void k_scan1(const unsigned* __restrict__ hist, unsigned* __restrict__ bbase,
                        unsigned* __restrict__ spart) {
    int t = threadIdx.x, blk = blockIdx.x;
    int i0 = blk * 1024 + t * 4;
    uint4 h = *(const uint4*)(hist + i0);
    unsigned s = h.x + h.y + h.z + h.w;
    __shared__ unsigned sc[256];
    sc[t] = s; __syncthreads();
    for (int off = 1; off < 256; off <<= 1) {
        unsigned v = (t >= off) ? sc[t - off] : 0u;
        __syncthreads(); sc[t] += v; __syncthreads();
    }
    unsigned excl = sc[t] - s;
    if (t == 255) spart[blk] = sc[255];
    uint4 o; o.x = excl; o.y = o.x + h.x; o.z = o.y + h.y; o.w = o.z + h.z;
    *(uint4*)(bbase + i0) = o;
}

// load spart[0..31] and build exclusive prefix in LDS (wave-0 shfl scan)
__device__ __forceinline__ void spart_prefix(const unsigned* __restrict__ spart,
                                             unsigned* sp) {
    int t = threadIdx.x;
    if (t < 64) {
        unsigned v = (t < 32) ? spart[t] : 0u;
        unsigned incl = v;
        for (int off = 1; off < 32; off <<= 1) {
            unsigned w = __shfl_up(incl, off, 64);
            if (t >= off) incl += w;
        }
        if (t < 32) sp[t] = incl - v;
    }
    __syncthreads();
}

// C: scatter node ids into bucket slots (global base = sp[b>>10] + consumed bbase)
__global__ void k_scatter(const double* __restrict__ score_d, const unsigned* __restrict__ spart,
                          unsigned* __restrict__ bbase, unsigned* __restrict__ elems) {
    __shared__ unsigned sp[32];
    spart_prefix(spart, sp);
    int i = blockIdx.x * 256 + threadIdx.x;
    if (i >= NNODES) return;
    int b = bucketOf(score_d[i]);
    unsigned slot = sp[b >> 10] + atomicAdd(&bbase[b], 1u);
    elems[slot] = (unsigned)i;
}

// R: exact rank (desc, tie -> lower idx); perm + region/batch + keep bits
// post-scatter: bbase[b] = local_excl + hist[b] => st = sp[b>>10] + bbase[b] - hist[b]
__global__ void k_rank(const double* __restrict__ score_d, const unsigned* __restrict__ hist,
                       const unsigned* __restrict__ bbase, const unsigned* __restrict__ spart,
                       const unsigned* __restrict__ elems, const int* __restrict__ region,
                       const int* __restrict__ batch, unsigned* __restrict__ perm,
                       unsigned* __restrict__ kb, float* __restrict__ out) {
    __shared__ unsigned sp[32];
    spart_prefix(spart, sp);
    int i = blockIdx.x * 256 + threadIdx.x;
    if (i >= NNODES) return;
    double s = score_d[i];
    int b = bucketOf(s);
    unsigned c = hist[b];
    unsigned st = sp[b >> 10] + bbase[b] - c;
    unsigned r = st;
    if (c > 1) {
        for (unsigned m = 0; m < c; ++m) {
            unsigned j = elems[st + m];
            if (j == (unsigned)i) continue;
            double sj = score_d[j];
            if (sj > s || (sj == s && j < (unsigned)i)) r++;
        }
    }
    if (r < KPOOL) {
        perm[r] = (unsigned)i;
        out[OFF_REG + r] = (float)region[i];
        out[OFF_BAT + r] = (float)batch[i];
        atomicOr(&kb[i >> 5], 1u << (i & 31));
    }
}

// P+C: pool gather (32 lanes x float4 per row) fused with edge chunk counting
__global__ void k_poolcnt(const float* __restrict__ x, const unsigned* __restrict__ perm,
                          const int* __restrict__ ei, const unsigned* __restrict__ kb,
                          unsigned* __restrict__ epart, float* __restrict__ out) {
    int tid = threadIdx.x, bid = blockIdx.x;
    if (bid < NBE) {
        // count kept edges in chunk bid (2048 edges, 8/thread, ei reads only)
        size_t e0 = (size_t)bid * EPB + (size_t)tid * 8;
        unsigned cnt = 0;
        if (e0 + 8 <= (size_t)NEDGES) {      // 8-edge granules fully in or out
            int4 a0 = *(const int4*)(ei + e0);
            int4 a1 = *(const int4*)(ei + e0 + 4);
            int4 b0 = *(const int4*)(ei + NEDGES + e0);
            int4 b1 = *(const int4*)(ei + NEDGES + e0 + 4);
            cnt += (kb[a0.x >> 5] >> (a0.x & 31)) & (kb[b0.x >> 5] >> (b0.x & 31)) & 1u;
            cnt += (kb[a0.y >> 5] >> (a0.y & 31)) & (kb[b0.y >> 5] >> (b0.y & 31)) & 1u;
            cnt += (kb[a0.z >> 5] >> (a0.z & 31)) & (kb[b0.z >> 5] >> (b0.z & 31)) & 1u;
            cnt += (kb[a0.w >> 5] >> (a0.w & 31)) & (kb[b0.w >> 5] >> (b0.w & 31)) & 1u;
            cnt += (kb[a1.x >> 5] >> (a1.x & 31)) & (kb[b1.x >> 5] >> (b1.x & 31)) & 1u;
            cnt += (kb[a1.y >> 5] >> (a1.y & 31)) & (kb[b1.y >> 5] >> (b1.y & 31)) & 1u;
            cnt += (kb[a1.z >> 5] >> (a1.z & 31)) & (kb[b1.z >> 5] >> (b1.z & 31)) & 1u;
            cnt += (kb[a1.w >> 5] >> (a1.w & 31)) & (kb[b1.w >> 5] >> (b1.w & 31)) & 1u;
        }
        __shared__ unsigned sc[256];
        sc[tid] = cnt; __syncthreads();
        for (int off = 128; off > 0; off >>= 1) {
            if (tid < off) sc[tid] += sc[tid + off];
            __syncthreads();
        }
        if (tid == 0) epart[bid] = sc[0];
    } else {
        // pool: 8 rows/block, 32 lanes x float4 per row (16B/lane, coalesced)
        int r = (bid - NBE) * 8 + (tid >> 5);
        int l = tid & 31;
        unsigned i = perm[r];
        float4 v = *(const float4*)(x + (size_t)i * CH + l * 4);
        *(float4*)(out + OFF_X + (size_t)r * CH + l * 4) = v;
    }
}

// E: stable edge compaction; per-block prefix from epart (L2-hot), no handshakes
__global__ __launch_bounds__(256, 4) void k_escatter(
        const int* __restrict__ ei, const float* __restrict__ attr,
        const unsigned* __restrict__ kb, const unsigned* __restrict__ epart,
        float* __restrict__ out) {
    int tid = threadIdx.x, bid = blockIdx.x;
    int lane = tid & 63, wid = tid >> 6;
    __shared__ unsigned sc[256];
    __shared__ unsigned wtot[4];
    __shared__ float sA[EPB], sB[EPB], sT[EPB];
    size_t e0 = (size_t)bid * EPB + (size_t)tid * 8;
    int av[8], bv[8]; float tv[8];
    unsigned m = 0;
    if (e0 + 8 <= (size_t)NEDGES) {
        int4 a0 = *(const int4*)(ei + e0);
        int4 a1 = *(const int4*)(ei + e0 + 4);
        int4 b0 = *(const int4*)(ei + NEDGES + e0);
        int4 b1 = *(const int4*)(ei + NEDGES + e0 + 4);
        float4 t0 = *(const float4*)(attr + e0);
        float4 t1 = *(const float4*)(attr + e0 + 4);
        av[0]=a0.x; av[1]=a0.y; av[2]=a0.z; av[3]=a0.w;
        av[4]=a1.x; av[5]=a1.y; av[6]=a1.z; av[7]=a1.w;
        bv[0]=b0.x; bv[1]=b0.y; bv[2]=b0.z; bv[3]=b0.w;
        bv[4]=b1.x; bv[5]=b1.y; bv[6]=b1.z; bv[7]=b1.w;
        tv[0]=t0.x; tv[1]=t0.y; tv[2]=t0.z; tv[3]=t0.w;
        tv[4]=t1.x; tv[5]=t1.y; tv[6]=t1.z; tv[7]=t1.w;
#pragma unroll
        for (int q = 0; q < 8; ++q) {
            unsigned k = (kb[av[q] >> 5] >> (av[q] & 31)) &
                         (kb[bv[q] >> 5] >> (bv[q] & 31)) & 1u;
            m |= k << q;
        }
    }
    unsigned cnt = __popc(m);
    // wave-level inclusive scan (shfl)
    unsigned incl = cnt;
    for (int off = 1; off < 64; off <<= 1) {
        unsigned v = __shfl_up(incl, off, 64);
        if (lane >= off) incl += v;
    }
    if (lane == 63) wtot[wid] = incl;
    // per-block global prefix + grand total from epart (6.3 KB, L2-hot)
    unsigned mypr = 0, myttl = 0;
    for (int j = tid; j < NBE; j += 256) {
        unsigned v = epart[j];
        myttl += v;
        if (j < bid) mypr += v;
    }
    __syncthreads();
    unsigned wpre = 0, btot = 0;
#pragma unroll
    for (int w = 0; w < 4; ++w) { unsigned v = wtot[w]; if (w < wid) wpre += v; btot += v; }
    unsigned p = wpre + incl - cnt;
    sc[tid] = mypr; __syncthreads();
    for (int off = 128; off > 0; off >>= 1) {
        if (tid < off) sc[tid] += sc[tid + off];
        __syncthreads();
    }
    unsigned wbase = sc[0];
    __syncthreads();
    if (bid == 0) {
        sc[tid] = myttl; __syncthreads();
        for (int off = 128; off > 0; off >>= 1) {
            if (tid < off) sc[tid] += sc[tid + off];
            __syncthreads();
        }
        if (tid == 0) out[OFF_NE] = (float)sc[0];
    }
    // stage kept edges (disjoint positions)
#pragma unroll
    for (int q = 0; q < 8; ++q) {
        if ((m >> q) & 1u) {
            sA[p] = (float)av[q]; sB[p] = (float)bv[q]; sT[p] = tv[q]; p++;
        }
    }
    __syncthreads();
    for (unsigned u = tid; u < btot; u += 256) {
        out[OFF_EI + wbase + u]          = sA[u];
        out[OFF_EI + NEDGES + wbase + u] = sB[u];
        out[OFF_EA + wbase + u]          = sT[u];
    }
    // tail [total, NEDGES) already prefilled with -1/-1/0 by k_scores_fill
}

extern "C" void kernel_launch(void* const* d_in, const int* in_sizes, int n_in,
                              void* d_out, int out_size, void* d_ws, size_t ws_size,
                              hipStream_t stream) {
    const float* x      = (const float*)d_in[0];
    const int*   ei     = (const int*)d_in[1];
    const float* attr   = (const float*)d_in[2];
    const int*   region = (const int*)d_in[3];
    const int*   batch  = (const int*)d_in[4];
    const float* W      = (const float*)d_in[5];
    const float* bias   = (const float*)d_in[6];
    float* out = (float*)d_out;

    char* ws = (char*)d_ws;
    double*   score_d = (double*)(ws + WS_SCORE);
    unsigned* hist    = (unsigned*)(ws + WS_HIST);
    unsigned* kb      = (unsigned*)(ws + WS_KB);
    unsigned* bbase   = (unsigned*)(ws + WS_BBASE);
    unsigned* spart   = (unsigned*)(ws + WS_SPART);
    unsigned* elems   = (unsigned*)(ws + WS_ELEMS);
    unsigned* perm    = (unsigned*)(ws + WS_PERM);
    unsigned* epart   = (unsigned*)(ws + WS_EPART);

    k_init       <<<(ZERO_U4 + 255) / 256, 256, 0, stream>>>((uint4*)(ws + WS_HIST));
    k_scores_fill<<<SCORE_BLK + FILL_BLK, 256, 0, stream>>>(x, W, bias, score_d, out, hist);
    k_scan1      <<<32, 256, 0, stream>>>(hist, bbase, spart);
    k_scatter    <<<(NNODES + 255) / 256, 256, 0, stream>>>(score_d, spart, bbase, elems);
    k_rank       <<<(NNODES + 255) / 256, 256, 0, stream>>>(score_d, hist, bbase, spart, elems,
                                                            region, batch, perm, kb, out);
    k_poolcnt    <<<NBE + POOLG, 256, 0, stream>>>(x, perm, ei, kb, epart, out);
    k_escatter   <<<NBE, 256, 0, stream>>>(ei, attr, kb, epart, out);
}